// Round 4
// baseline (1557.858 us; speedup 1.0000x reference)
//
#include <hip/hip_runtime.h>
#include <hip/hip_bf16.h>

#define NN 100000
#define DIN 128
#define DOUT 256
#define RR 4
#define EE 600000
#define NB (RR * NN)
#define SCAN_BLKS 400
#define SCAN_CHUNK 1000

typedef __attribute__((ext_vector_type(4))) float f32x4;
typedef __attribute__((ext_vector_type(8))) short short8;
typedef __attribute__((ext_vector_type(2))) uint uint2v;

__device__ __forceinline__ float bf2f(ushort u) {
    union { unsigned int i; float f; } v; v.i = ((unsigned int)u) << 16; return v.f;
}
__device__ __forceinline__ ushort f2bf(float f) {
    union { float f; unsigned int i; } v; v.f = f;
    unsigned int r = v.i + 0x7fff + ((v.i >> 16) & 1);  // RNE
    return (ushort)(r >> 16);
}

__device__ __forceinline__ void ld_g2l16(const void* g, void* l) {
    __builtin_amdgcn_global_load_lds(
        (const __attribute__((address_space(1))) void*)g,
        (__attribute__((address_space(3))) void*)l, 16, 0, 0);
}

// ---------------- weight prep: out[(kd/64)*256*64 + o*64 + kd%64] = 0.25*sum_r in[r][o][k]
__global__ void wprep(const float* __restrict__ in, ushort* __restrict__ out,
                      int K, int nsum, long sumstride, int kbase) {
    int idx = blockIdx.x * blockDim.x + threadIdx.x;
    if (idx >= K * 256) return;
    int k = idx >> 8, o = idx & 255;
    float s = 0.f;
    for (int r = 0; r < nsum; ++r) s += in[r * sumstride + (long)o * K + k];
    s *= 0.25f;  // fold mean over RR relations into weights
    int kd = kbase + k;
    out[((size_t)(kd >> 6) * 256 + o) * 64 + (kd & 63)] = f2bf(s);
}

__global__ void bias_sum(const float* __restrict__ b, float* __restrict__ bs, int O, int nr) {
    int o = blockIdx.x * blockDim.x + threadIdx.x;
    if (o >= O) return;
    float s = 0.f;
    for (int r = 0; r < nr; ++r) s += b[(long)r * O + o];
    bs[o] = s * 0.25f;
}

// ---------------- CSR build ----------------
__global__ void deg_count(const int* __restrict__ ei, int* __restrict__ deg) {
    int idx = blockIdx.x * blockDim.x + threadIdx.x;
    if (idx >= RR * EE) return;
    int r = idx / EE, e = idx - r * EE;
    int dst = ei[(size_t)r * 2 * EE + EE + e];
    atomicAdd(&deg[r * NN + dst], 1);
}

__global__ __launch_bounds__(256) void scan_part(const int* __restrict__ deg,
                                                 int* __restrict__ bsum) {
    int b = blockIdx.x, t = threadIdx.x;
    int s = 0;
    for (int i = t; i < SCAN_CHUNK; i += 256) s += deg[b * SCAN_CHUNK + i];
    for (int o = 32; o > 0; o >>= 1) s += __shfl_down(s, o);
    __shared__ int red[4];
    if ((t & 63) == 0) red[t >> 6] = s;
    __syncthreads();
    if (t == 0) bsum[b] = red[0] + red[1] + red[2] + red[3];
}

__global__ __launch_bounds__(512) void scan_top(int* __restrict__ bsum) {
    __shared__ int v[512];
    int t = threadIdx.x;
    v[t] = (t < SCAN_BLKS) ? bsum[t] : 0;
    __syncthreads();
    for (int st = 1; st < 512; st <<= 1) {
        int tmp = (t >= st) ? v[t - st] : 0;
        __syncthreads();
        v[t] += tmp;
        __syncthreads();
    }
    if (t < SCAN_BLKS) bsum[t] = (t == 0) ? 0 : v[t - 1];  // exclusive
}

__global__ __launch_bounds__(256) void scan_final(const int* __restrict__ deg,
                                                  const int* __restrict__ bsum,
                                                  int* __restrict__ off) {
    __shared__ int lv[1024];
    __shared__ int ts[256];
    int b = blockIdx.x, t = threadIdx.x;
    for (int i = t; i < 1024; i += 256)
        lv[i] = (i < SCAN_CHUNK) ? deg[b * SCAN_CHUNK + i] : 0;
    __syncthreads();
    int i0 = t * 4;
    int v0 = lv[i0], v1 = lv[i0 + 1], v2 = lv[i0 + 2], v3 = lv[i0 + 3];
    ts[t] = v0 + v1 + v2 + v3;
    __syncthreads();
    for (int st = 1; st < 256; st <<= 1) {
        int tmp = (t >= st) ? ts[t - st] : 0;
        __syncthreads();
        ts[t] += tmp;
        __syncthreads();
    }
    int run = bsum[b] + (t ? ts[t - 1] : 0);
    if (i0 < SCAN_CHUNK) {
        off[b * SCAN_CHUNK + i0 + 0] = run; run += v0;
        off[b * SCAN_CHUNK + i0 + 1] = run; run += v1;
        off[b * SCAN_CHUNK + i0 + 2] = run; run += v2;
        off[b * SCAN_CHUNK + i0 + 3] = run; run += v3;
    }
    if (b == SCAN_BLKS - 1 && t == 255) off[NB] = bsum[b] + ts[255];
}

__global__ void fill_csr(const int* __restrict__ ei, int* __restrict__ cursor,
                         int* __restrict__ elist) {
    int idx = blockIdx.x * blockDim.x + threadIdx.x;
    if (idx >= RR * EE) return;
    int r = idx / EE, e = idx - r * EE;
    int src = ei[(size_t)r * 2 * EE + e];
    int dst = ei[(size_t)r * 2 * EE + EE + e];
    int p = atomicAdd(&cursor[r * NN + dst], 1);
    elist[p] = src;
}

// ---------------- fp32 x -> compact bf16 table XB [NN][128] ----------------
__global__ void cvt_x(const float* __restrict__ x, ushort* __restrict__ XB) {
    int t = blockIdx.x * blockDim.x + threadIdx.x;
    if (t >= NN * 32) return;
    int n = t >> 5, c4 = (t & 31) * 4;
    float4 v = *(const float4*)&x[(size_t)n * 128 + c4];
    ushort4 o = {f2bf(v.x), f2bf(v.y), f2bf(v.z), f2bf(v.w)};
    *(ushort4*)&XB[(size_t)n * 128 + c4] = o;
}

// ---------------- gather: agg[n][rl*D+d] = sum_src feat[src][d]; NT store ----------------
template <int D>
__global__ void gather_bf16(const ushort* __restrict__ feat,
                            const int* __restrict__ elist, const int* __restrict__ off,
                            ushort* __restrict__ agg, int sout, int chunk) {
    constexpr int V = D / 64;  // ushorts per lane
    int wv = blockIdx.x * 4 + (threadIdx.x >> 6);
    int lane = threadIdx.x & 63;
    if (wv >= NN * chunk) return;
    int n = wv / chunk, rl = wv - n * chunk;
    int b = rl * NN + n;
    int beg = off[b], end = off[b + 1];
    float acc[V];
#pragma unroll
    for (int v = 0; v < V; ++v) acc[v] = 0.f;
    int e = beg;
    for (; e + 2 <= end; e += 2) {
        int s0 = elist[e], s1 = elist[e + 1];
        const ushort* p0 = feat + (size_t)s0 * D + lane * V;
        const ushort* p1 = feat + (size_t)s1 * D + lane * V;
        if constexpr (V == 2) {
            ushort2 a = *(const ushort2*)p0, c = *(const ushort2*)p1;
            acc[0] += bf2f(a.x) + bf2f(c.x);
            acc[1] += bf2f(a.y) + bf2f(c.y);
        } else {
            ushort4 a = *(const ushort4*)p0, c = *(const ushort4*)p1;
            acc[0] += bf2f(a.x) + bf2f(c.x);
            acc[1] += bf2f(a.y) + bf2f(c.y);
            acc[2] += bf2f(a.z) + bf2f(c.z);
            acc[3] += bf2f(a.w) + bf2f(c.w);
        }
    }
    if (e < end) {
        int s0 = elist[e];
        const ushort* p0 = feat + (size_t)s0 * D + lane * V;
        if constexpr (V == 2) {
            ushort2 a = *(const ushort2*)p0;
            acc[0] += bf2f(a.x); acc[1] += bf2f(a.y);
        } else {
            ushort4 a = *(const ushort4*)p0;
            acc[0] += bf2f(a.x); acc[1] += bf2f(a.y);
            acc[2] += bf2f(a.z); acc[3] += bf2f(a.w);
        }
    }
    ushort* op = agg + (size_t)n * sout + rl * D + lane * V;
    if constexpr (V == 2) {
        uint u = (uint)f2bf(acc[0]) | ((uint)f2bf(acc[1]) << 16);
        __builtin_nontemporal_store(u, (uint*)op);
    } else {
        uint2v u;
        u.x = (uint)f2bf(acc[0]) | ((uint)f2bf(acc[1]) << 16);
        u.y = (uint)f2bf(acc[2]) | ((uint)f2bf(acc[3]) << 16);
        __builtin_nontemporal_store(u, (uint2v*)op);
    }
}

// ---------------- split-A bf16 MFMA GEMM ----------------
// A = concat(F [M,ldf] cols 0..K1, G [M,ldg] cols K1..K1+K2); W prescaled [Kt/64][256][64].
// MODE 0: Cout = float*, NT store of acc+bias.
// MODE 1: Cout = ushort* (bf16), fused bias + l2norm + relu epilogue.
template <int MODE>
__global__ __launch_bounds__(256) void gemm_mfma(
    const ushort* __restrict__ F, int ldf, int K1,
    const ushort* __restrict__ G, int ldg, int K2,
    const ushort* __restrict__ W, const float* __restrict__ bias,
    void* __restrict__ Cout, int M) {
    union SM {
        struct { ushort lA[128 * 64]; ushort lB[256 * 64]; } s;          // 48 KB
        struct { float rowsq[2][128]; uint stgw[MODE ? 128 * 136 : 1]; } e;
    };
    __shared__ SM sm;
    const int tid = threadIdx.x;
    const int w = tid >> 6, lane = tid & 63;
    const int wr = w >> 1, wc = w & 1;
    const int row0 = blockIdx.x * 128;

    f32x4 acc[4][8];
#pragma unroll
    for (int i = 0; i < 4; ++i)
#pragma unroll
        for (int j = 0; j < 8; ++j) acc[i][j] = {0.f, 0.f, 0.f, 0.f};

    const int arow = lane >> 3;
    const int acol = (lane & 7) * 8;
    const int Ktot = K1 + K2;

    for (int k0 = 0; k0 < Ktot; k0 += 64) {
        __syncthreads();
        const ushort* src; int ld; int kk;
        if (k0 < K1) { src = F; ld = ldf; kk = k0; }
        else         { src = G; ld = ldg; kk = k0 - K1; }
#pragma unroll
        for (int c = 0; c < 4; ++c) {
            int r = w * 32 + c * 8 + arow;
            ld_g2l16(src + (size_t)(row0 + r) * ld + kk + acol, &sm.s.lA[r * 64 + acol]);
        }
        const ushort* wb = W + (size_t)(k0 >> 6) * (256 * 64);
#pragma unroll
        for (int c = 0; c < 8; ++c) {
            int o = (w * 8 + c) * 512 + lane * 8;
            ld_g2l16(wb + o, &sm.s.lB[o]);
        }
        asm volatile("s_waitcnt vmcnt(0)" ::: "memory");
        __syncthreads();
#pragma unroll
        for (int ks = 0; ks < 2; ++ks) {
            const int ko = ks * 32 + (lane >> 4) * 8;
            short8 af[4];
#pragma unroll
            for (int rf = 0; rf < 4; ++rf)
                af[rf] = *(const short8*)&sm.s.lA[(wr * 64 + rf * 16 + (lane & 15)) * 64 + ko];
#pragma unroll
            for (int cf = 0; cf < 8; ++cf) {
                short8 bfrag = *(const short8*)&sm.s.lB[(wc * 128 + cf * 16 + (lane & 15)) * 64 + ko];
#pragma unroll
                for (int rf = 0; rf < 4; ++rf)
                    acc[rf][cf] = __builtin_amdgcn_mfma_f32_16x16x32_bf16(
                        af[rf], bfrag, acc[rf][cf], 0, 0, 0);
            }
        }
    }

    if constexpr (MODE == 0) {
        float* Cf = (float*)Cout;
        const int rb0 = row0 + wr * 64 + (lane >> 4) * 4;
        const int cb0 = wc * 128 + (lane & 15);
#pragma unroll
        for (int cf = 0; cf < 8; ++cf) {
            int col = cb0 + cf * 16;
            float badd = bias ? bias[col] : 0.f;
#pragma unroll
            for (int rf = 0; rf < 4; ++rf)
#pragma unroll
                for (int m = 0; m < 4; ++m) {
                    int r = rb0 + rf * 16 + m;
                    if (r < M)
                        __builtin_nontemporal_store(acc[rf][cf][m] + badd,
                                                    &Cf[(size_t)r * 256 + col]);
                }
        }
    } else {
        // fused: bias add -> row sumsq -> l2norm -> relu -> bf16 -> coalesced store
        __syncthreads();  // all waves done reading lA/lB before union reuse
        const int cb0 = wc * 128 + (lane & 15);
#pragma unroll
        for (int cf = 0; cf < 8; ++cf) {
            float badd = bias[cb0 + cf * 16];
#pragma unroll
            for (int rf = 0; rf < 4; ++rf)
#pragma unroll
                for (int m = 0; m < 4; ++m) acc[rf][cf][m] += badd;
        }
        float ss[4][4];
#pragma unroll
        for (int rf = 0; rf < 4; ++rf)
#pragma unroll
            for (int m = 0; m < 4; ++m) {
                float s = 0.f;
#pragma unroll
                for (int cf = 0; cf < 8; ++cf) s += acc[rf][cf][m] * acc[rf][cf][m];
#pragma unroll
                for (int o = 1; o < 16; o <<= 1) s += __shfl_xor(s, o);
                ss[rf][m] = s;
            }
        if ((lane & 15) == 0) {
#pragma unroll
            for (int rf = 0; rf < 4; ++rf)
#pragma unroll
                for (int m = 0; m < 4; ++m)
                    sm.e.rowsq[wc][wr * 64 + rf * 16 + (lane >> 4) * 4 + m] = ss[rf][m];
        }
        __syncthreads();
#pragma unroll
        for (int rf = 0; rf < 4; ++rf)
#pragma unroll
            for (int m = 0; m < 4; ++m) {
                int tr = wr * 64 + rf * 16 + (lane >> 4) * 4 + m;
                float tot = sm.e.rowsq[0][tr] + sm.e.rowsq[1][tr];
                ss[rf][m] = 1.0f / fmaxf(sqrtf(tot), 1e-12f);
            }
        // pack adjacent-column bf16 pairs; stride 136 words keeps rows on disjoint banks
#pragma unroll
        for (int rf = 0; rf < 4; ++rf)
#pragma unroll
            for (int m = 0; m < 4; ++m) {
                int tr = wr * 64 + rf * 16 + (lane >> 4) * 4 + m;
                float inv = ss[rf][m];
#pragma unroll
                for (int cf = 0; cf < 8; ++cf) {
                    float v = fmaxf(acc[rf][cf][m] * inv, 0.f);
                    uint u = f2bf(v);
                    uint pu = __shfl_xor(u, 1);
                    if (!(lane & 1))
                        sm.e.stgw[tr * 136 + (wc * 64 + cf * 8 + ((lane & 15) >> 1))] =
                            u | (pu << 16);
                }
            }
        __syncthreads();
        uint* HBw = (uint*)Cout;
#pragma unroll
        for (int i = 0; i < 64; ++i) {
            int idx = tid + i * 256;
            int row = idx >> 7, cw = idx & 127;
            if (row0 + row < M)
                HBw[(size_t)(row0 + row) * 128 + cw] = sm.e.stgw[row * 136 + cw];
        }
    }
}

extern "C" void kernel_launch(void* const* d_in, const int* in_sizes, int n_in,
                              void* d_out, int out_size, void* d_ws, size_t ws_size,
                              hipStream_t stream) {
    const float* x   = (const float*)d_in[0];
    const int*   ei  = (const int*)d_in[1];
    const float* W1n = (const float*)d_in[2];
    const float* b1  = (const float*)d_in[3];
    const float* W1r = (const float*)d_in[4];
    const float* W2n = (const float*)d_in[5];
    const float* b2  = (const float*)d_in[6];
    const float* W2r = (const float*)d_in[7];

    // ---- ws layout (XB overlaid on G2: lifetimes disjoint) ----
    ushort* HB  = (ushort*)d_ws;                       // [NN][256] bf16 h table
    ushort* G1  = HB + (size_t)NN * 256;               // [NN][512] layer-1 aggs
    ushort* G2  = G1 + (size_t)NN * 512;               // [NN][1024] layer-2 aggs
    ushort* XB  = G2;                                  // [NN][128] bf16 x (dies before G2 lives)
    int* elist  = (int*)(G2 + (size_t)NN * 1024);      // RR*EE
    int* degc   = elist + (size_t)RR * EE;             // NB
    int* off    = degc + NB;                           // NB+1
    int* bsum   = off + NB + 1;                        // 512
    ushort* W1c = (ushort*)(bsum + 512);               // 640*256
    ushort* W2c = W1c + 640 * 256;                     // 1280*256
    float* b1s  = (float*)(W2c + 1280 * 256);
    float* b2s  = b1s + 256;

    const int nE = RR * EE;

    // ---- CSR build ----
    hipMemsetAsync(degc, 0, (size_t)NB * sizeof(int), stream);
    deg_count<<<(nE + 255) / 256, 256, 0, stream>>>(ei, degc);
    scan_part<<<SCAN_BLKS, 256, 0, stream>>>(degc, bsum);
    scan_top<<<1, 512, 0, stream>>>(bsum);
    scan_final<<<SCAN_BLKS, 256, 0, stream>>>(degc, bsum, off);
    hipMemcpyAsync(degc, off, (size_t)NB * sizeof(int), hipMemcpyDeviceToDevice, stream);
    fill_csr<<<(nE + 255) / 256, 256, 0, stream>>>(ei, degc, elist);

    // ---- weight prep (bf16, MFMA layout, prescaled by 0.25) ----
    wprep<<<128, 256, 0, stream>>>(W1r, W1c, 128, RR, (long)DOUT * DIN, 0);
    for (int r = 0; r < RR; ++r)
        wprep<<<128, 256, 0, stream>>>(W1n + (size_t)r * DOUT * DIN, W1c, 128, 1, 0,
                                       128 + r * 128);
    wprep<<<256, 256, 0, stream>>>(W2r, W2c, 256, RR, (long)DOUT * DOUT, 0);
    for (int r = 0; r < RR; ++r)
        wprep<<<256, 256, 0, stream>>>(W2n + (size_t)r * DOUT * DOUT, W2c, 256, 1, 0,
                                       256 + r * 256);
    bias_sum<<<1, 256, 0, stream>>>(b1, b1s, 256, RR);
    bias_sum<<<1, 256, 0, stream>>>(b2, b2s, 256, RR);

    cvt_x<<<(NN * 32 + 255) / 256, 256, 0, stream>>>(x, XB);

    const int ggrid = (NN + 127) / 128;

    // ---- layer 1: HB = relu(l2norm(0.25*(x·W1r_sum + Σ_r agg_r(x)·W1n_r + b1_sum))) ----
    gather_bf16<128><<<NN, 256, 0, stream>>>(XB, elist, off, G1, 512, RR);
    gemm_mfma<1><<<ggrid, 256, 0, stream>>>(XB, 128, 128, G1, 512, 512, W1c, b1s, HB, NN);

    // ---- layer 2: out = 0.25*(h·W2r_sum + Σ_r agg_r(h)·W2n_r + b2_sum) ----
    gather_bf16<256><<<NN, 256, 0, stream>>>(HB, elist, off, G2, 1024, RR);
    gemm_mfma<0><<<ggrid, 256, 0, stream>>>(HB, 256, 256, G2, 1024, 1024, W2c, b2s,
                                            d_out, NN);
}

// Round 5
// 924.832 us; speedup vs baseline: 1.6845x; 1.6845x over previous
//
#include <hip/hip_runtime.h>
#include <hip/hip_bf16.h>

#define NN 100000
#define DIN 128
#define DOUT 256
#define RR 4
#define EE 600000
#define NB (RR * NN)
#define SCAN_BLKS 400
#define SCAN_CHUNK 1000

typedef __attribute__((ext_vector_type(4))) float f32x4;
typedef __attribute__((ext_vector_type(8))) short short8;
typedef __attribute__((ext_vector_type(2))) uint uint2v;

__device__ __forceinline__ float bf2f(ushort u) {
    union { unsigned int i; float f; } v; v.i = ((unsigned int)u) << 16; return v.f;
}
__device__ __forceinline__ ushort f2bf(float f) {
    union { float f; unsigned int i; } v; v.f = f;
    unsigned int r = v.i + 0x7fff + ((v.i >> 16) & 1);  // RNE
    return (ushort)(r >> 16);
}

__device__ __forceinline__ void ld_g2l16(const void* g, void* l) {
    __builtin_amdgcn_global_load_lds(
        (const __attribute__((address_space(1))) void*)g,
        (__attribute__((address_space(3))) void*)l, 16, 0, 0);
}

// ---------------- weight prep ----------------
// logical W[kd][o] = 0.25*sum_r in[r][o][k]; stored swizzled:
// block kd>>6, within-row chunk c=(kd>>3)&7 stored at slot c^(o&7), elem kd&7.
__global__ void wprep(const float* __restrict__ in, ushort* __restrict__ out,
                      int K, int nsum, long sumstride, int kbase) {
    int idx = blockIdx.x * blockDim.x + threadIdx.x;
    if (idx >= K * 256) return;
    int k = idx >> 8, o = idx & 255;
    float s = 0.f;
    for (int r = 0; r < nsum; ++r) s += in[r * sumstride + (long)o * K + k];
    s *= 0.25f;  // fold mean over RR relations into weights
    int kd = kbase + k;
    int cs = ((kd >> 3) & 7) ^ (o & 7);
    out[((size_t)(kd >> 6) * 256 + o) * 64 + cs * 8 + (kd & 7)] = f2bf(s);
}

__global__ void bias_sum(const float* __restrict__ b, float* __restrict__ bs, int O, int nr) {
    int o = blockIdx.x * blockDim.x + threadIdx.x;
    if (o >= O) return;
    float s = 0.f;
    for (int r = 0; r < nr; ++r) s += b[(long)r * O + o];
    bs[o] = s * 0.25f;
}

// ---------------- CSR build ----------------
__global__ void deg_count(const int* __restrict__ ei, int* __restrict__ deg) {
    int idx = blockIdx.x * blockDim.x + threadIdx.x;
    if (idx >= RR * EE) return;
    int r = idx / EE, e = idx - r * EE;
    int dst = ei[(size_t)r * 2 * EE + EE + e];
    atomicAdd(&deg[r * NN + dst], 1);
}

__global__ __launch_bounds__(256) void scan_part(const int* __restrict__ deg,
                                                 int* __restrict__ bsum) {
    int b = blockIdx.x, t = threadIdx.x;
    int s = 0;
    for (int i = t; i < SCAN_CHUNK; i += 256) s += deg[b * SCAN_CHUNK + i];
    for (int o = 32; o > 0; o >>= 1) s += __shfl_down(s, o);
    __shared__ int red[4];
    if ((t & 63) == 0) red[t >> 6] = s;
    __syncthreads();
    if (t == 0) bsum[b] = red[0] + red[1] + red[2] + red[3];
}

__global__ __launch_bounds__(512) void scan_top(int* __restrict__ bsum) {
    __shared__ int v[512];
    int t = threadIdx.x;
    v[t] = (t < SCAN_BLKS) ? bsum[t] : 0;
    __syncthreads();
    for (int st = 1; st < 512; st <<= 1) {
        int tmp = (t >= st) ? v[t - st] : 0;
        __syncthreads();
        v[t] += tmp;
        __syncthreads();
    }
    if (t < SCAN_BLKS) bsum[t] = (t == 0) ? 0 : v[t - 1];  // exclusive
}

__global__ __launch_bounds__(256) void scan_final(const int* __restrict__ deg,
                                                  const int* __restrict__ bsum,
                                                  int* __restrict__ off) {
    __shared__ int lv[1024];
    __shared__ int ts[256];
    int b = blockIdx.x, t = threadIdx.x;
    for (int i = t; i < 1024; i += 256)
        lv[i] = (i < SCAN_CHUNK) ? deg[b * SCAN_CHUNK + i] : 0;
    __syncthreads();
    int i0 = t * 4;
    int v0 = lv[i0], v1 = lv[i0 + 1], v2 = lv[i0 + 2], v3 = lv[i0 + 3];
    ts[t] = v0 + v1 + v2 + v3;
    __syncthreads();
    for (int st = 1; st < 256; st <<= 1) {
        int tmp = (t >= st) ? ts[t - st] : 0;
        __syncthreads();
        ts[t] += tmp;
        __syncthreads();
    }
    int run = bsum[b] + (t ? ts[t - 1] : 0);
    if (i0 < SCAN_CHUNK) {
        off[b * SCAN_CHUNK + i0 + 0] = run; run += v0;
        off[b * SCAN_CHUNK + i0 + 1] = run; run += v1;
        off[b * SCAN_CHUNK + i0 + 2] = run; run += v2;
        off[b * SCAN_CHUNK + i0 + 3] = run; run += v3;
    }
    if (b == SCAN_BLKS - 1 && t == 255) off[NB] = bsum[b] + ts[255];
}

__global__ void fill_csr(const int* __restrict__ ei, int* __restrict__ cursor,
                         int* __restrict__ elist) {
    int idx = blockIdx.x * blockDim.x + threadIdx.x;
    if (idx >= RR * EE) return;
    int r = idx / EE, e = idx - r * EE;
    int src = ei[(size_t)r * 2 * EE + e];
    int dst = ei[(size_t)r * 2 * EE + EE + e];
    int p = atomicAdd(&cursor[r * NN + dst], 1);
    elist[p] = src;
}

// ---------------- fp32 x -> compact bf16 table XB [NN][128] ----------------
__global__ void cvt_x(const float* __restrict__ x, ushort* __restrict__ XB) {
    int t = blockIdx.x * blockDim.x + threadIdx.x;
    if (t >= NN * 32) return;
    int n = t >> 5, c4 = (t & 31) * 4;
    float4 v = *(const float4*)&x[(size_t)n * 128 + c4];
    ushort4 o = {f2bf(v.x), f2bf(v.y), f2bf(v.z), f2bf(v.w)};
    *(ushort4*)&XB[(size_t)n * 128 + c4] = o;
}

// ---------------- gather: agg[n][rl*D+d] = sum_src feat[src][d]; NT store ----------------
template <int D>
__global__ void gather_bf16(const ushort* __restrict__ feat,
                            const int* __restrict__ elist, const int* __restrict__ off,
                            ushort* __restrict__ agg, int sout, int chunk) {
    constexpr int V = D / 64;  // ushorts per lane
    int wv = blockIdx.x * 4 + (threadIdx.x >> 6);
    int lane = threadIdx.x & 63;
    if (wv >= NN * chunk) return;
    int n = wv / chunk, rl = wv - n * chunk;
    int b = rl * NN + n;
    int beg = off[b], end = off[b + 1];
    float acc[V];
#pragma unroll
    for (int v = 0; v < V; ++v) acc[v] = 0.f;
    int e = beg;
    for (; e + 2 <= end; e += 2) {
        int s0 = elist[e], s1 = elist[e + 1];
        const ushort* p0 = feat + (size_t)s0 * D + lane * V;
        const ushort* p1 = feat + (size_t)s1 * D + lane * V;
        if constexpr (V == 2) {
            ushort2 a = *(const ushort2*)p0, c = *(const ushort2*)p1;
            acc[0] += bf2f(a.x) + bf2f(c.x);
            acc[1] += bf2f(a.y) + bf2f(c.y);
        } else {
            ushort4 a = *(const ushort4*)p0, c = *(const ushort4*)p1;
            acc[0] += bf2f(a.x) + bf2f(c.x);
            acc[1] += bf2f(a.y) + bf2f(c.y);
            acc[2] += bf2f(a.z) + bf2f(c.z);
            acc[3] += bf2f(a.w) + bf2f(c.w);
        }
    }
    if (e < end) {
        int s0 = elist[e];
        const ushort* p0 = feat + (size_t)s0 * D + lane * V;
        if constexpr (V == 2) {
            ushort2 a = *(const ushort2*)p0;
            acc[0] += bf2f(a.x); acc[1] += bf2f(a.y);
        } else {
            ushort4 a = *(const ushort4*)p0;
            acc[0] += bf2f(a.x); acc[1] += bf2f(a.y);
            acc[2] += bf2f(a.z); acc[3] += bf2f(a.w);
        }
    }
    ushort* op = agg + (size_t)n * sout + rl * D + lane * V;
    if constexpr (V == 2) {
        uint u = (uint)f2bf(acc[0]) | ((uint)f2bf(acc[1]) << 16);
        __builtin_nontemporal_store(u, (uint*)op);
    } else {
        uint2v u;
        u.x = (uint)f2bf(acc[0]) | ((uint)f2bf(acc[1]) << 16);
        u.y = (uint)f2bf(acc[2]) | ((uint)f2bf(acc[3]) << 16);
        __builtin_nontemporal_store(u, (uint2v*)op);
    }
}

// ---------------- split-A bf16 MFMA GEMM, 256x256 tile, 8 waves, dbuf + swizzle ------
// A = concat(F [M,ldf] K1 cols, G [M,ldg] K2 cols); W swizzled [Kt/64][256][64].
// MODE 0: Cout=float*, NT stores. MODE 1: Cout=ushort* bf16, fused l2norm+relu.
template <int MODE>
__global__ __launch_bounds__(512, 2) void gemm_mfma(
    const ushort* __restrict__ F, int ldf, int K1,
    const ushort* __restrict__ G, int ldg, int K2,
    const ushort* __restrict__ W, const float* __restrict__ bias,
    void* __restrict__ Cout, int M) {
    union SM {
        ushort buf[2][2][256 * 64];  // [dbuf][A/B][row*64 + slot*8 + e]  128 KiB
        float rowsq[2][256];
    };
    __shared__ SM sm;
    const int tid = threadIdx.x;
    const int w = tid >> 6, lane = tid & 63;
    const int wr = w >> 1, wc = w & 1;       // wave grid: 4 row x 2 col
    const int row0 = blockIdx.x * 256;

    f32x4 acc[4][8];
#pragma unroll
    for (int i = 0; i < 4; ++i)
#pragma unroll
        for (int j = 0; j < 8; ++j) acc[i][j] = {0.f, 0.f, 0.f, 0.f};

    // staging: 4 instrs per wave each for A and B; instr c covers rows w*32+c*8..+7
    const int arow = lane >> 3;                       // 0..7 within 8-row group
    const int asrc = ((lane & 7) ^ arow) << 3;        // swizzled source chunk offset
    const ushort* aF[4]; const ushort* aG[4];
#pragma unroll
    for (int c = 0; c < 4; ++c) {
        int rg = row0 + w * 32 + c * 8 + arow;
        if (rg > M - 1) rg = M - 1;                   // clamp: values unused, stay in-bounds
        aF[c] = F + (size_t)rg * ldf + asrc;
        aG[c] = G + (size_t)rg * ldg + asrc;
    }
    const int ldst = lane * 8;                        // linear LDS dest (ushorts)
    const int nt = (K1 + K2) >> 6;

    auto STAGE = [&](int b, int kt) {
        int kb = kt << 6;
        const ushort* wb = W + (size_t)kt * (256 * 64);
#pragma unroll
        for (int c = 0; c < 4; ++c) {
            const ushort* src = (kb < K1) ? (aF[c] + kb) : (aG[c] + (kb - K1));
            ld_g2l16(src, &sm.buf[b][0][(w * 32 + c * 8) * 64 + ldst]);
            ld_g2l16(wb + (w * 32 + c * 8) * 64 + ldst,
                     &sm.buf[b][1][(w * 32 + c * 8) * 64 + ldst]);
        }
    };

    STAGE(0, 0);
    asm volatile("s_waitcnt vmcnt(0)" ::: "memory");
    __syncthreads();

    int cur = 0;
    for (int t = 0; t < nt; ++t) {
        if (t + 1 < nt) STAGE(cur ^ 1, t + 1);
        __builtin_amdgcn_s_setprio(1);
#pragma unroll
        for (int ks = 0; ks < 2; ++ks) {
            const int co = (((ks * 4 + (lane >> 4)) ^ (lane & 7)) << 3);  // swizzled read
            short8 af[4];
#pragma unroll
            for (int rf = 0; rf < 4; ++rf)
                af[rf] = *(const short8*)&sm.buf[cur][0]
                             [(wr * 64 + rf * 16 + (lane & 15)) * 64 + co];
#pragma unroll
            for (int cf = 0; cf < 8; ++cf) {
                short8 bf8 = *(const short8*)&sm.buf[cur][1]
                                 [(wc * 128 + cf * 16 + (lane & 15)) * 64 + co];
#pragma unroll
                for (int rf = 0; rf < 4; ++rf)
                    acc[rf][cf] = __builtin_amdgcn_mfma_f32_16x16x32_bf16(
                        af[rf], bf8, acc[rf][cf], 0, 0, 0);
            }
        }
        __builtin_amdgcn_s_setprio(0);
        asm volatile("s_waitcnt vmcnt(0)" ::: "memory");
        __syncthreads();
        cur ^= 1;
    }

    const int rb0 = row0 + wr * 64 + (lane >> 4) * 4;
    const int cb0 = wc * 128 + (lane & 15);
    if constexpr (MODE == 0) {
        float* Cf = (float*)Cout;
#pragma unroll
        for (int cf = 0; cf < 8; ++cf) {
            int col = cb0 + cf * 16;
            float badd = bias[col];
#pragma unroll
            for (int rf = 0; rf < 4; ++rf)
#pragma unroll
                for (int m = 0; m < 4; ++m) {
                    int r = rb0 + rf * 16 + m;
                    if (r < M)
                        __builtin_nontemporal_store(acc[rf][cf][m] + badd,
                                                    &Cf[(size_t)r * 256 + col]);
                }
        }
    } else {
        // fused: bias -> row sumsq -> l2norm -> relu -> bf16 packed store
#pragma unroll
        for (int cf = 0; cf < 8; ++cf) {
            float badd = bias[cb0 + cf * 16];
#pragma unroll
            for (int rf = 0; rf < 4; ++rf)
#pragma unroll
                for (int m = 0; m < 4; ++m) acc[rf][cf][m] += badd;
        }
        float ss[4][4];
#pragma unroll
        for (int rf = 0; rf < 4; ++rf)
#pragma unroll
            for (int m = 0; m < 4; ++m) {
                float s = 0.f;
#pragma unroll
                for (int cf = 0; cf < 8; ++cf) s += acc[rf][cf][m] * acc[rf][cf][m];
#pragma unroll
                for (int o = 1; o < 16; o <<= 1) s += __shfl_xor(s, o);
                ss[rf][m] = s;
            }
        // final loop barrier already passed; safe to reuse LDS via union
        if ((lane & 15) == 0) {
#pragma unroll
            for (int rf = 0; rf < 4; ++rf)
#pragma unroll
                for (int m = 0; m < 4; ++m)
                    sm.rowsq[wc][wr * 64 + rf * 16 + (lane >> 4) * 4 + m] = ss[rf][m];
        }
        __syncthreads();
        uint* HBw = (uint*)Cout;
#pragma unroll
        for (int rf = 0; rf < 4; ++rf)
#pragma unroll
            for (int m = 0; m < 4; ++m) {
                int tr = wr * 64 + rf * 16 + (lane >> 4) * 4 + m;
                float inv = 1.0f / fmaxf(sqrtf(sm.rowsq[0][tr] + sm.rowsq[1][tr]), 1e-12f);
                int r = row0 + tr;
#pragma unroll
                for (int cf = 0; cf < 8; ++cf) {
                    float v = fmaxf(acc[rf][cf][m] * inv, 0.f);
                    uint u = f2bf(v);
                    uint pu = __shfl_xor(u, 1);
                    if (!(lane & 1) && r < M)
                        HBw[(size_t)r * 128 + ((cb0 + cf * 16) >> 1)] = u | (pu << 16);
                }
            }
    }
}

extern "C" void kernel_launch(void* const* d_in, const int* in_sizes, int n_in,
                              void* d_out, int out_size, void* d_ws, size_t ws_size,
                              hipStream_t stream) {
    const float* x   = (const float*)d_in[0];
    const int*   ei  = (const int*)d_in[1];
    const float* W1n = (const float*)d_in[2];
    const float* b1  = (const float*)d_in[3];
    const float* W1r = (const float*)d_in[4];
    const float* W2n = (const float*)d_in[5];
    const float* b2  = (const float*)d_in[6];
    const float* W2r = (const float*)d_in[7];

    // ---- ws layout (XB overlaid on G2: lifetimes disjoint) ----
    ushort* HB  = (ushort*)d_ws;                       // [NN][256] bf16 h table
    ushort* G1  = HB + (size_t)NN * 256;               // [NN][512] layer-1 aggs
    ushort* G2  = G1 + (size_t)NN * 512;               // [NN][1024] layer-2 aggs
    ushort* XB  = G2;                                  // [NN][128] bf16 x (dies before G2 lives)
    int* elist  = (int*)(G2 + (size_t)NN * 1024);      // RR*EE
    int* degc   = elist + (size_t)RR * EE;             // NB
    int* off    = degc + NB;                           // NB+1
    int* bsum   = off + NB + 1;                        // 512
    ushort* W1c = (ushort*)(bsum + 512);               // 640*256
    ushort* W2c = W1c + 640 * 256;                     // 1280*256
    float* b1s  = (float*)(W2c + 1280 * 256);
    float* b2s  = b1s + 256;

    const int nE = RR * EE;

    // ---- CSR build ----
    hipMemsetAsync(degc, 0, (size_t)NB * sizeof(int), stream);
    deg_count<<<(nE + 255) / 256, 256, 0, stream>>>(ei, degc);
    scan_part<<<SCAN_BLKS, 256, 0, stream>>>(degc, bsum);
    scan_top<<<1, 512, 0, stream>>>(bsum);
    scan_final<<<SCAN_BLKS, 256, 0, stream>>>(degc, bsum, off);
    hipMemcpyAsync(degc, off, (size_t)NB * sizeof(int), hipMemcpyDeviceToDevice, stream);
    fill_csr<<<(nE + 255) / 256, 256, 0, stream>>>(ei, degc, elist);

    // ---- weight prep (bf16, swizzled MFMA layout, prescaled 0.25) ----
    wprep<<<128, 256, 0, stream>>>(W1r, W1c, 128, RR, (long)DOUT * DIN, 0);
    for (int r = 0; r < RR; ++r)
        wprep<<<128, 256, 0, stream>>>(W1n + (size_t)r * DOUT * DIN, W1c, 128, 1, 0,
                                       128 + r * 128);
    wprep<<<256, 256, 0, stream>>>(W2r, W2c, 256, RR, (long)DOUT * DOUT, 0);
    for (int r = 0; r < RR; ++r)
        wprep<<<256, 256, 0, stream>>>(W2n + (size_t)r * DOUT * DOUT, W2c, 256, 1, 0,
                                       256 + r * 256);
    bias_sum<<<1, 256, 0, stream>>>(b1, b1s, 256, RR);
    bias_sum<<<1, 256, 0, stream>>>(b2, b2s, 256, RR);

    cvt_x<<<(NN * 32 + 255) / 256, 256, 0, stream>>>(x, XB);

    const int ggrid = (NN + 255) / 256;

    // ---- layer 1: HB = relu(l2norm(0.25*(x·W1r_sum + Σ_r agg_r(x)·W1n_r) + b1s)) ----
    gather_bf16<128><<<NN, 256, 0, stream>>>(XB, elist, off, G1, 512, RR);
    gemm_mfma<1><<<ggrid, 512, 0, stream>>>(XB, 128, 128, G1, 512, 512, W1c, b1s, HB, NN);

    // ---- layer 2: out = 0.25*(h·W2r_sum + Σ_r agg_r(h)·W2n_r) + b2s ----
    gather_bf16<256><<<NN, 256, 0, stream>>>(HB, elist, off, G2, 1024, RR);
    gemm_mfma<0><<<ggrid, 512, 0, stream>>>(HB, 256, 256, G2, 1024, 1024, W2c, b2s,
                                            d_out, NN);
}